// Round 1
// 323.355 us; speedup vs baseline: 1.2319x; 1.2319x over previous
//
#include <hip/hip_runtime.h>

typedef unsigned short u16;
typedef unsigned int   u32;

// RESOLVED (rounds 0-10): d_out is FLOAT32. Inputs f32. din=128, hd=128
// (H=2, dout=64), N=in_sizes[0]/128, NE=in_sizes[1]/2.
// Outputs flat f32: H_out [0,N*64) ; E [N*64,+2NE) ; attr [+NE).
// R11: edge_fused 178us (VALU 59%, occ 81%); gemm1 est ~60us LDS-pipe-bound.
// R12: gemm1 -> bf16 MFMA; edge_fused 8-deep gather MLP; 394us total.
// R13: edge_fused was DS-pipe/issue-bound (12 shfl+12 add butterfly per edge,
//      192 DS/node final linear; HBM 9%). Restructure: natural head-major row
//      layout, ONE NODE PER 32-LANE HALF (4 ch/lane, head = 16-lane group) ->
//      4-step shfl reduce serving 2 edges/wave-inst; final linear via packed
//      uint4 Wf (2x ds_read_b128 per k4) per half-wave, no trailing barrier.

#define DIN   128
#define DOUT  64
#define HD    128   // H * DOUT

typedef __attribute__((ext_vector_type(8))) short  bf16x8;
typedef __attribute__((ext_vector_type(4))) float  f32x4;

__device__ __forceinline__ u16 f2b(float f) {
    union { float f; u32 i; } u; u.f = f;
    u32 r = u.i + 0x7FFFu + ((u.i >> 16) & 1u);   // RNE
    return (u16)(r >> 16);
}
__device__ __forceinline__ float lo_bf(u32 p) {
    union { u32 i; float f; } x; x.i = p << 16; return x.f;
}
__device__ __forceinline__ float hi_bf(u32 p) {
    union { u32 i; float f; } x; x.i = p & 0xFFFF0000u; return x.f;
}

// ---------------------------------------------------------------------------
// K1: MFMA GEMM  dst = bf16(X[N x 128] @ W[128 x 128] + b), natural layout:
// dst[node*128 + c], c = head*64 + ch  (matches att/bias flat indexing).
// Grid (ceil(N/64), 2): cb=0 -> W_l -> xl_p ; cb=1 -> W_r -> xr_p.
// LDS: A 64x128 bf16 (stride 136), B^T 128x128 bf16 (stride 136) = 51 KB.
// ---------------------------------------------------------------------------
__global__ __launch_bounds__(256) void gemm1(
    const float* __restrict__ X, const float* __restrict__ Wl, const float* __restrict__ bl,
    const float* __restrict__ Wr, const float* __restrict__ br,
    u16* __restrict__ xl_p, u16* __restrict__ xr_p, int N)
{
    __shared__ u16 sA[64 * 136];    // [row][k]  17408 B
    __shared__ u16 sB[128 * 136];   // [col][k]  34816 B (transposed W)

    const int tid  = threadIdx.x;
    const int row0 = blockIdx.x * 64;
    const int cb   = blockIdx.y;
    const float* W   = (cb == 0) ? Wl : Wr;
    const float* bia = (cb == 0) ? bl : br;

    // stage A: X rows -> bf16 (8B packed stores)
    for (int idx = tid; idx < 64 * 32; idx += 256) {
        int r  = idx >> 5;
        int k4 = (idx & 31) << 2;
        int gr = row0 + r;
        float4 v = make_float4(0.f, 0.f, 0.f, 0.f);
        if (gr < N) v = *(const float4*)(X + (size_t)gr * DIN + k4);
        u32 p0 = (u32)f2b(v.x) | ((u32)f2b(v.y) << 16);
        u32 p1 = (u32)f2b(v.z) | ((u32)f2b(v.w) << 16);
        *(uint2*)&sA[r * 136 + k4] = make_uint2(p0, p1);
    }
    // stage B transposed: sB[n][k] = bf16(W[k][n])
    for (int idx = tid; idx < 128 * 32; idx += 256) {
        int k  = idx >> 5;
        int n4 = (idx & 31) << 2;
        float4 v = *(const float4*)(W + k * HD + n4);
        sB[(n4 + 0) * 136 + k] = f2b(v.x);
        sB[(n4 + 1) * 136 + k] = f2b(v.y);
        sB[(n4 + 2) * 136 + k] = f2b(v.z);
        sB[(n4 + 3) * 136 + k] = f2b(v.w);
    }
    __syncthreads();

    const int wv   = tid >> 6;
    const int lane = tid & 63;
    const int m    = lane & 15;
    const int quad = lane >> 4;
    const int arow = wv * 16 + m;

    f32x4 acc[8] = {};
    #pragma unroll
    for (int kc = 0; kc < 4; kc++) {
        bf16x8 a = *(const bf16x8*)&sA[arow * 136 + kc * 32 + quad * 8];
        #pragma unroll
        for (int t = 0; t < 8; t++) {
            bf16x8 b = *(const bf16x8*)&sB[(t * 16 + m) * 136 + kc * 32 + quad * 8];
            acc[t] = __builtin_amdgcn_mfma_f32_16x16x32_bf16(a, b, acc[t], 0, 0, 0);
        }
    }

    u16* dst = (cb == 0) ? xl_p : xr_p;
    #pragma unroll
    for (int t = 0; t < 8; t++) {
        const int c    = t * 16 + m;         // hd index 0..127 (head*64+ch)
        const float bj = bia[c];
        #pragma unroll
        for (int r = 0; r < 4; r++) {
            int gr = row0 + wv * 16 + quad * 4 + r;
            if (gr < N)
                dst[(size_t)gr * HD + c] = f2b(acc[t][r] + bj);
        }
    }
}

// ---------------------------------------------------------------------------
// CSR build
// ---------------------------------------------------------------------------
__global__ void init_counts(int* count, int* cursor, int N) {
    int n = blockIdx.x * blockDim.x + threadIdx.x;
    if (n < N) { count[n] = 1; cursor[n] = 0; }   // 1 = self loop
}

__global__ void hist(const int* __restrict__ E, int* count, int N, int NE) {
    int e = blockIdx.x * blockDim.x + threadIdx.x;
    if (e < NE) {
        int d = E[NE + e];
        if ((u32)d >= (u32)N) d = 0;
        atomicAdd(&count[d], 1);
    }
}

// ---- 3-phase parallel exclusive scan ----
__global__ __launch_bounds__(256) void scan1(const int* __restrict__ count,
                                             int* __restrict__ bsum, int N) {
    __shared__ int s[256];
    int t = threadIdx.x;
    int idx = blockIdx.x * 256 + t;
    s[t] = (idx < N) ? count[idx] : 0;
    __syncthreads();
    for (int d = 128; d; d >>= 1) {
        if (t < d) s[t] += s[t + d];
        __syncthreads();
    }
    if (t == 0) bsum[blockIdx.x] = s[0];
}

__global__ __launch_bounds__(1024) void scan2(const int* __restrict__ bsum,
                                              int* __restrict__ bsum_ex, int G) {
    __shared__ int s[1024];
    int t = threadIdx.x;
    s[t] = (t < G) ? bsum[t] : 0;
    __syncthreads();
    for (int d = 1; d < 1024; d <<= 1) {
        int v = (t >= d) ? s[t - d] : 0;
        __syncthreads();
        s[t] += v;
        __syncthreads();
    }
    if (t < G) bsum_ex[t] = (t > 0) ? s[t - 1] : 0;
}

__global__ __launch_bounds__(256) void scan3(const int* __restrict__ count,
                                             const int* __restrict__ bsum_ex,
                                             int* __restrict__ offsets, int N) {
    __shared__ int s[256];
    int t = threadIdx.x;
    int idx = blockIdx.x * 256 + t;
    int v = (idx < N) ? count[idx] : 0;
    s[t] = v;
    __syncthreads();
    for (int d = 1; d < 256; d <<= 1) {
        int u = (t >= d) ? s[t - d] : 0;
        __syncthreads();
        s[t] += u;
        __syncthreads();
    }
    if (idx < N) offsets[idx] = bsum_ex[blockIdx.x] + s[t] - v;
}

__global__ void scatter(const int* __restrict__ E, const int* __restrict__ offsets,
                        int* cursor, int* __restrict__ src_sorted,
                        int N, int NE, int ET) {
    int e = blockIdx.x * blockDim.x + threadIdx.x;
    if (e >= ET) return;
    int src, dst;
    if (e < NE) {
        src = E[e];
        dst = E[NE + e];
        if ((u32)dst >= (u32)N) dst = 0;     // same clamp as hist
    } else {
        src = dst = e - NE;
    }
    int pos = atomicAdd(&cursor[dst], 1);
    int slot = offsets[dst] + pos;
    if ((u32)slot < (u32)ET) src_sorted[slot] = src;
}

// ---------------------------------------------------------------------------
// K3: fused edge softmax-aggregate + final linear + LayerNorm (H=2, dout=64).
// ONE NODE PER 32-LANE HALF-WAVE. Lane hl owns entries 4hl..4hl+3 (head =
// hl>>4, i.e. each 16-lane group owns one head). Score reduce = 4 xor steps
// within 16 lanes; each wave instruction serves 2 edges (one per half).
// Gathers: uint2 (8B/lane x 32 lanes = coalesced 256B row), 8 in flight.
// Final linear: packed uint4 Wf in LDS (both col-halves + 4 k per read),
// per-half-wave with wave-local LDS handoff (no block barrier after stage).
// ---------------------------------------------------------------------------
__global__ __launch_bounds__(256, 6) void edge_fused(
    const u16* __restrict__ xl_p, const u16* __restrict__ xr_p,
    const float* __restrict__ att, const float* __restrict__ bias,
    const float* __restrict__ Wf, const float* __restrict__ bf,
    const float* __restrict__ gamma, const float* __restrict__ beta,
    const int* __restrict__ offsets, const int* __restrict__ count,
    const int* __restrict__ src_sorted, float* __restrict__ out,
    int N, int ET)
{
    // sWp[k4*32+c] = { pack(Wf[4k4+0][c],Wf[4k4+1][c]),
    //                  pack(Wf[4k4+2][c],Wf[4k4+3][c]),
    //                  pack(Wf[4k4+0][c+32],Wf[4k4+1][c+32]),
    //                  pack(Wf[4k4+2][c+32],Wf[4k4+3][c+32]) }
    __shared__ uint4 sWp[32 * 32];      // 16 KB
    __shared__ float sAgg[8][HD];       // 4 KB

    const int tid = threadIdx.x;
    for (int idx = tid; idx < 32 * 32; idx += 256) {
        int k4 = idx >> 5, c = idx & 31;
        const float* wrow = Wf + (size_t)(4 * k4) * DOUT;
        u32 a0 = (u32)f2b(wrow[c])               | ((u32)f2b(wrow[DOUT + c]) << 16);
        u32 a1 = (u32)f2b(wrow[2 * DOUT + c])    | ((u32)f2b(wrow[3 * DOUT + c]) << 16);
        u32 a2 = (u32)f2b(wrow[c + 32])          | ((u32)f2b(wrow[DOUT + c + 32]) << 16);
        u32 a3 = (u32)f2b(wrow[2 * DOUT + c + 32]) | ((u32)f2b(wrow[3 * DOUT + c + 32]) << 16);
        sWp[idx] = make_uint4(a0, a1, a2, a3);
    }
    __syncthreads();   // only barrier: sWp staged; everything after is per-half

    const int half = tid >> 5;          // node slot 0..7 in block
    const int hl   = tid & 31;          // lane within half
    const int n    = blockIdx.x * 8 + half;
    const bool active = (n < N);

    float xr[4] = {0.f, 0.f, 0.f, 0.f};
    if (active) {
        uint2 pr = *(const uint2*)(xr_p + (size_t)n * HD + hl * 4);
        xr[0] = lo_bf(pr.x); xr[1] = hi_bf(pr.x);
        xr[2] = lo_bf(pr.y); xr[3] = hi_bf(pr.y);
    }
    // fold log2(e) into att so exp(s) == exp2(dot)
    float4 at4 = *(const float4*)(att + hl * 4);
    at4.x *= 1.44269504f; at4.y *= 1.44269504f;
    at4.z *= 1.44269504f; at4.w *= 1.44269504f;

    float acc[4] = {0.f, 0.f, 0.f, 0.f};
    float l = 0.f;

    int beg = 0, cnt = 0;
    if (active) {
        beg = offsets[n];
        cnt = count[n];
        if ((u32)beg >= (u32)ET) beg = 0;
        if (cnt < 0) cnt = 0;
        if (cnt > ET - beg) cnt = ET - beg;
    }

    const char* xbase = (const char*)xl_p + hl * 8;   // lane's 8B within any row

    int done = 0;
    while (done < cnt) {
        int chunk = cnt - done; if (chunk > 32) chunk = 32;
        int myidx = 0;
        if (hl < chunk) myidx = src_sorted[beg + done + hl];  // coalesced
        int j = 0;
        for (; j + 8 <= chunk; j += 8) {
            uint2 q[8];
            #pragma unroll
            for (int b = 0; b < 8; b++) {
                u32 off = (u32)__shfl(myidx, j + b, 32) << 8;   // row byte offset
                q[b] = *(const uint2*)(xbase + off);
            }
            float sh[8];
            #pragma unroll
            for (int b = 0; b < 8; b++) {
                float t0 = lo_bf(q[b].x) + xr[0]; t0 = fmaxf(t0, 0.2f * t0);
                float t1 = hi_bf(q[b].x) + xr[1]; t1 = fmaxf(t1, 0.2f * t1);
                float t2 = lo_bf(q[b].y) + xr[2]; t2 = fmaxf(t2, 0.2f * t2);
                float t3 = hi_bf(q[b].y) + xr[3]; t3 = fmaxf(t3, 0.2f * t3);
                sh[b] = fmaf(t0, at4.x, fmaf(t1, at4.y, fmaf(t2, at4.z, t3 * at4.w)));
            }
            #pragma unroll
            for (int m = 8; m; m >>= 1) {
                #pragma unroll
                for (int b = 0; b < 8; b++) sh[b] += __shfl_xor(sh[b], m);
            }
            #pragma unroll
            for (int b = 0; b < 8; b++) {
                float p = exp2f(sh[b]);
                l += p;
                acc[0] = fmaf(p, lo_bf(q[b].x), acc[0]);
                acc[1] = fmaf(p, hi_bf(q[b].x), acc[1]);
                acc[2] = fmaf(p, lo_bf(q[b].y), acc[2]);
                acc[3] = fmaf(p, hi_bf(q[b].y), acc[3]);
            }
        }
        for (; j < chunk; j++) {
            u32 off = (u32)__shfl(myidx, j, 32) << 8;
            uint2 q = *(const uint2*)(xbase + off);
            float t0 = lo_bf(q.x) + xr[0]; t0 = fmaxf(t0, 0.2f * t0);
            float t1 = hi_bf(q.x) + xr[1]; t1 = fmaxf(t1, 0.2f * t1);
            float t2 = lo_bf(q.y) + xr[2]; t2 = fmaxf(t2, 0.2f * t2);
            float t3 = hi_bf(q.y) + xr[3]; t3 = fmaxf(t3, 0.2f * t3);
            float s = fmaf(t0, at4.x, fmaf(t1, at4.y, fmaf(t2, at4.z, t3 * at4.w)));
            #pragma unroll
            for (int m = 8; m; m >>= 1) s += __shfl_xor(s, m);
            float p = exp2f(s);
            l += p;
            acc[0] = fmaf(p, lo_bf(q.x), acc[0]);
            acc[1] = fmaf(p, hi_bf(q.x), acc[1]);
            acc[2] = fmaf(p, lo_bf(q.y), acc[2]);
            acc[3] = fmaf(p, hi_bf(q.y), acc[3]);
        }
        done += chunk;
    }

    // normalize + bias, park in this half's sAgg slot (wave-local handoff)
    float rl = 1.f / fmaxf(l, 1e-30f);
    float4 bv = *(const float4*)(bias + hl * 4);
    f32x4 agg;
    agg[0] = acc[0] * rl + bv.x; agg[1] = acc[1] * rl + bv.y;
    agg[2] = acc[2] * rl + bv.z; agg[3] = acc[3] * rl + bv.w;
    *(f32x4*)&sAgg[half][hl * 4] = agg;
    asm volatile("s_waitcnt lgkmcnt(0)" ::: "memory");   // same-wave DS visibility

    // final linear: lane hl computes channels hl and hl+32
    float h0 = bf[hl], h1 = bf[hl + 32];
    #pragma unroll 8
    for (int k4 = 0; k4 < 32; k4++) {
        uint4 wp = sWp[k4 * 32 + hl];
        f32x4 ag = *(const f32x4*)&sAgg[half][k4 * 4];
        h0 = fmaf(ag[0], lo_bf(wp.x), h0);
        h0 = fmaf(ag[1], hi_bf(wp.x), h0);
        h0 = fmaf(ag[2], lo_bf(wp.y), h0);
        h0 = fmaf(ag[3], hi_bf(wp.y), h0);
        h1 = fmaf(ag[0], lo_bf(wp.z), h1);
        h1 = fmaf(ag[1], hi_bf(wp.z), h1);
        h1 = fmaf(ag[2], lo_bf(wp.w), h1);
        h1 = fmaf(ag[3], hi_bf(wp.w), h1);
    }

    float s1r = h0 + h1, s2r = h0 * h0 + h1 * h1;
    #pragma unroll
    for (int m = 16; m; m >>= 1) { s1r += __shfl_xor(s1r, m); s2r += __shfl_xor(s2r, m); }
    float mu  = s1r * (1.f / 64.f);
    float var = s2r * (1.f / 64.f) - mu * mu;
    float rs  = rsqrtf(fmaxf(var, 0.f) + 1e-5f);
    if (active) {
        out[(size_t)n * DOUT + hl]      = (h0 - mu) * rs * gamma[hl]      + beta[hl];
        out[(size_t)n * DOUT + hl + 32] = (h1 - mu) * rs * gamma[hl + 32] + beta[hl + 32];
    }
}

// ---------------------------------------------------------------------------
// K5: passthrough of E (int -> f32) and attr (f32 copy) at f32 base N*64
// ---------------------------------------------------------------------------
__global__ void passthrough(const int* __restrict__ E, const float* __restrict__ attr,
                            float* __restrict__ out, int N, int NE) {
    int i = blockIdx.x * blockDim.x + threadIdx.x;
    const size_t base = (size_t)N * DOUT;
    if (i < 2 * NE) {
        out[base + i] = (float)E[i];
    } else {
        int j = i - 2 * NE;
        if (j < NE) out[base + 2 * (size_t)NE + j] = attr[j];
    }
}

// ---------------------------------------------------------------------------
extern "C" void kernel_launch(void* const* d_in, const int* in_sizes, int n_in,
                              void* d_out, int out_size, void* d_ws, size_t ws_size,
                              hipStream_t stream) {
    const float* X    = (const float*)d_in[0];
    const int*   E    = (const int*)d_in[1];
    const float* attr = (const float*)d_in[2];
    const float* Wl   = (const float*)d_in[3];
    const float* bl   = (const float*)d_in[4];
    const float* Wr   = (const float*)d_in[5];
    const float* br   = (const float*)d_in[6];
    const float* att  = (const float*)d_in[7];
    const float* bias = (const float*)d_in[8];
    const float* Wf   = (const float*)d_in[9];
    const float* bf   = (const float*)d_in[10];
    const float* gamma= (const float*)d_in[11];
    const float* beta = (const float*)d_in[12];
    float* out = (float*)d_out;

    const int N  = in_sizes[0] / DIN;
    const int NE = in_sizes[1] / 2;
    const int ET = NE + N;
    const int G  = (N + 255) / 256;   // scan blocks

    char* ws = (char*)d_ws;
    int* count      = (int*)ws;               ws += (size_t)N * 4;
    int* cursor     = (int*)ws;               ws += (size_t)N * 4;
    int* offsets    = (int*)ws;               ws += (size_t)N * 4;
    int* bsum       = (int*)ws;               ws += (size_t)G * 4;
    int* bsum_ex    = (int*)ws;               ws += (size_t)G * 4;
    int* src_sorted = (int*)ws;               ws += (size_t)ET * 4;
    u16* xl_p       = (u16*)ws;               ws += (size_t)N * HD * 2;
    u16* xr_p       = (u16*)ws;               ws += (size_t)N * HD * 2;

    passthrough<<<(3 * NE + 255) / 256, 256, 0, stream>>>(E, attr, out, N, NE);

    gemm1<<<dim3((N + 63) / 64, 2), 256, 0, stream>>>(X, Wl, bl, Wr, br, xl_p, xr_p, N);
    init_counts<<<(N + 255) / 256, 256, 0, stream>>>(count, cursor, N);
    hist<<<(NE + 255) / 256, 256, 0, stream>>>(E, count, N, NE);
    scan1<<<G, 256, 0, stream>>>(count, bsum, N);
    scan2<<<1, 1024, 0, stream>>>(bsum, bsum_ex, G);
    scan3<<<G, 256, 0, stream>>>(count, bsum_ex, offsets, N);
    scatter<<<(ET + 255) / 256, 256, 0, stream>>>(E, offsets, cursor, src_sorted, N, NE, ET);

    edge_fused<<<(N + 7) / 8, 256, 0, stream>>>(
        xl_p, xr_p, att, bias, Wf, bf, gamma, beta,
        offsets, count, src_sorted, out, N, ET);
}

// Round 3
// 316.100 us; speedup vs baseline: 1.2602x; 1.0230x over previous
//
#include <hip/hip_runtime.h>

typedef unsigned short u16;
typedef unsigned int   u32;

// RESOLVED (rounds 0-10): d_out is FLOAT32. Inputs f32. din=128, hd=128
// (H=2, dout=64), N=in_sizes[0]/128, NE=in_sizes[1]/2.
// Outputs flat f32: H_out [0,N*64) ; E [N*64,+2NE) ; attr [+NE).
// R13: edge_fused 182->99us via half-wave/node + 4-step reduce. Total 323.
// R14: edge_fused -> 16 lanes/edge, uint4 gathers (1 VMEM inst = 4 edges,
//      3-step 8-lane reduce, DS/edge 2.5->1). gemm1: pre-transposed bf16 W
//      (aux kernel) kills 16-way LDS write conflict; MFMA operand swap
//      (A=W^T,B=X -> D col=node,row=ch) gives packed uint2 epilogue stores.
// R15: container failed twice on R14; only API-level change was
//      hipMemsetAsync inside kernel_launch (graph-capture hazard). Replaced
//      with zero_counts kernel; all R14 kernel code unchanged.

#define DIN   128
#define DOUT  64
#define HD    128   // H * DOUT

typedef __attribute__((ext_vector_type(8))) short  bf16x8;
typedef __attribute__((ext_vector_type(4))) float  f32x4;

__device__ __forceinline__ u16 f2b(float f) {
    union { float f; u32 i; } u; u.f = f;
    u32 r = u.i + 0x7FFFu + ((u.i >> 16) & 1u);   // RNE
    return (u16)(r >> 16);
}
__device__ __forceinline__ float lo_bf(u32 p) {
    union { u32 i; float f; } x; x.i = p << 16; return x.f;
}
__device__ __forceinline__ float hi_bf(u32 p) {
    union { u32 i; float f; } x; x.i = p & 0xFFFF0000u; return x.f;
}

__global__ void zero_counts(int* __restrict__ p, int n) {
    int i = blockIdx.x * blockDim.x + threadIdx.x;
    if (i < n) p[i] = 0;
}

// ---------------------------------------------------------------------------
// K0: aux  = W_l/W_r transpose->bf16  +  Wf pack (sWp layout)  +  edge hist
//      + E/attr passthrough.  Flat item space, one launch.
// WT[c*128+k] = bf16(W[k][c]);  Wfp[k4*32+c] = {pack(W[4k4][c],W[4k4+1][c]),
//   pack(W[4k4+2][c],W[4k4+3][c]), same for c+32}
// ---------------------------------------------------------------------------
__global__ void aux_prep(const float* __restrict__ Wl, const float* __restrict__ Wr,
                         const float* __restrict__ Wf,
                         const int* __restrict__ E, const float* __restrict__ attr,
                         u16* __restrict__ WTl, u16* __restrict__ WTr,
                         uint4* __restrict__ Wfp, int* __restrict__ count,
                         float* __restrict__ out, int N, int NE)
{
    int i = blockIdx.x * 256 + threadIdx.x;
    if (i < 16384) {                       // WTl
        int k = i >> 7, c = i & 127;
        WTl[c * 128 + k] = f2b(Wl[i]);     // i == k*128+c
    } else if (i < 32768) {                // WTr
        int j = i - 16384;
        int k = j >> 7, c = j & 127;
        WTr[c * 128 + k] = f2b(Wr[j]);
    } else if (i < 33792) {                // Wfp (1024 uint4)
        int j = i - 32768;
        int k4 = j >> 5, c = j & 31;
        const float* wrow = Wf + (size_t)(4 * k4) * DOUT;
        u32 a0 = (u32)f2b(wrow[c])              | ((u32)f2b(wrow[DOUT + c]) << 16);
        u32 a1 = (u32)f2b(wrow[2 * DOUT + c])   | ((u32)f2b(wrow[3 * DOUT + c]) << 16);
        u32 a2 = (u32)f2b(wrow[c + 32])         | ((u32)f2b(wrow[DOUT + c + 32]) << 16);
        u32 a3 = (u32)f2b(wrow[2 * DOUT + c + 32]) | ((u32)f2b(wrow[3 * DOUT + c + 32]) << 16);
        Wfp[j] = make_uint4(a0, a1, a2, a3);
    } else if (i < 33792 + NE) {           // hist (count pre-zeroed)
        int e = i - 33792;
        int d = E[NE + e];
        if ((u32)d >= (u32)N) d = 0;
        atomicAdd(&count[d], 1);
    } else {                               // passthrough
        int j = i - 33792 - NE;
        const size_t base = (size_t)N * DOUT;
        if (j < 2 * NE) {
            out[base + j] = (float)E[j];
        } else {
            int t = j - 2 * NE;
            if (t < NE) out[base + 2 * (size_t)NE + t] = attr[t];
        }
    }
}

// ---------------------------------------------------------------------------
// K1: MFMA GEMM  dst = bf16(X[N x 128] @ W[128 x 128] + b), natural layout
// dst[node*128 + c].  Operands swapped vs R12: A = W^T (rows=c), B = X
// (cols=node) -> D: col(lane&15)=node, row(quad*4+r)=c -> 4 consecutive c
// per lane -> packed uint2 stores.  sW staged from pre-transposed bf16 WT
// (plain uint4 copy, no bank conflict).  LDS 51 KB.
// ---------------------------------------------------------------------------
__global__ __launch_bounds__(256) void gemm1(
    const float* __restrict__ X,
    const u16* __restrict__ WTl, const float* __restrict__ bl,
    const u16* __restrict__ WTr, const float* __restrict__ br,
    u16* __restrict__ xl_p, u16* __restrict__ xr_p, int N)
{
    __shared__ u16 sX[64 * 136];    // [node][k]  17408 B
    __shared__ u16 sW[128 * 136];   // [c][k]     34816 B

    const int tid  = threadIdx.x;
    const int row0 = blockIdx.x * 64;
    const int cb   = blockIdx.y;
    const u16*   WT  = (cb == 0) ? WTl : WTr;
    const float* bia = (cb == 0) ? bl : br;

    // stage X rows -> bf16 (8B packed stores)
    for (int idx = tid; idx < 64 * 32; idx += 256) {
        int r  = idx >> 5;
        int k4 = (idx & 31) << 2;
        int gr = row0 + r;
        float4 v = make_float4(0.f, 0.f, 0.f, 0.f);
        if (gr < N) v = *(const float4*)(X + (size_t)gr * DIN + k4);
        u32 p0 = (u32)f2b(v.x) | ((u32)f2b(v.y) << 16);
        u32 p1 = (u32)f2b(v.z) | ((u32)f2b(v.w) << 16);
        *(uint2*)&sX[r * 136 + k4] = make_uint2(p0, p1);
    }
    // stage W^T: plain 16B copies, conflict-free
    for (int idx = tid; idx < 128 * 16; idx += 256) {
        int c  = idx >> 4;
        int k8 = (idx & 15) << 3;
        *(uint4*)&sW[c * 136 + k8] = *(const uint4*)&WT[c * 128 + k8];
    }
    __syncthreads();

    const int wv   = tid >> 6;
    const int lane = tid & 63;
    const int m    = lane & 15;
    const int quad = lane >> 4;

    f32x4 acc[8] = {};
    #pragma unroll
    for (int kc = 0; kc < 4; kc++) {
        bf16x8 bx = *(const bf16x8*)&sX[(wv * 16 + m) * 136 + kc * 32 + quad * 8];
        #pragma unroll
        for (int t = 0; t < 8; t++) {
            bf16x8 aw = *(const bf16x8*)&sW[(t * 16 + m) * 136 + kc * 32 + quad * 8];
            acc[t] = __builtin_amdgcn_mfma_f32_16x16x32_bf16(aw, bx, acc[t], 0, 0, 0);
        }
    }

    const int gn = row0 + wv * 16 + m;          // node (D col = lane&15)
    if (gn < N) {
        u16* dst = (cb == 0) ? xl_p : xr_p;
        #pragma unroll
        for (int t = 0; t < 8; t++) {
            const int c0 = t * 16 + quad * 4;   // D row = quad*4+r
            float4 bv = *(const float4*)(bia + c0);
            u32 p0 = (u32)f2b(acc[t][0] + bv.x) | ((u32)f2b(acc[t][1] + bv.y) << 16);
            u32 p1 = (u32)f2b(acc[t][2] + bv.z) | ((u32)f2b(acc[t][3] + bv.w) << 16);
            *(uint2*)(dst + (size_t)gn * HD + c0) = make_uint2(p0, p1);
        }
    }
}

// ---- 3-phase parallel exclusive scan (self-loop +1 folded in) ----
__global__ __launch_bounds__(256) void scan1(const int* __restrict__ count,
                                             int* __restrict__ bsum, int N) {
    __shared__ int s[256];
    int t = threadIdx.x;
    int idx = blockIdx.x * 256 + t;
    s[t] = (idx < N) ? count[idx] + 1 : 0;
    __syncthreads();
    for (int d = 128; d; d >>= 1) {
        if (t < d) s[t] += s[t + d];
        __syncthreads();
    }
    if (t == 0) bsum[blockIdx.x] = s[0];
}

__global__ __launch_bounds__(1024) void scan2(const int* __restrict__ bsum,
                                              int* __restrict__ bsum_ex, int G) {
    __shared__ int s[1024];
    int t = threadIdx.x;
    s[t] = (t < G) ? bsum[t] : 0;
    __syncthreads();
    for (int d = 1; d < 1024; d <<= 1) {
        int v = (t >= d) ? s[t - d] : 0;
        __syncthreads();
        s[t] += v;
        __syncthreads();
    }
    if (t < G) bsum_ex[t] = (t > 0) ? s[t - 1] : 0;
}

__global__ __launch_bounds__(256) void scan3(const int* __restrict__ count,
                                             const int* __restrict__ bsum_ex,
                                             int* __restrict__ offsets, int N) {
    __shared__ int s[256];
    int t = threadIdx.x;
    int idx = blockIdx.x * 256 + t;
    int v = (idx < N) ? count[idx] + 1 : 0;
    s[t] = v;
    __syncthreads();
    for (int d = 1; d < 256; d <<= 1) {
        int u = (t >= d) ? s[t - d] : 0;
        __syncthreads();
        s[t] += u;
        __syncthreads();
    }
    if (idx < N) offsets[idx] = bsum_ex[blockIdx.x] + s[t] - v;
}

__global__ void scatter(const int* __restrict__ E, const int* __restrict__ offsets,
                        int* cursor, int* __restrict__ src_sorted,
                        int N, int NE, int ET) {
    int e = blockIdx.x * blockDim.x + threadIdx.x;
    if (e >= ET) return;
    int src, dst;
    if (e < NE) {
        src = E[e];
        dst = E[NE + e];
        if ((u32)dst >= (u32)N) dst = 0;     // same clamp as hist
    } else {
        src = dst = e - NE;
    }
    int pos = atomicAdd(&cursor[dst], 1);
    int slot = offsets[dst] + pos;
    if ((u32)slot < (u32)ET) src_sorted[slot] = src;
}

// ---------------------------------------------------------------------------
// K3: fused edge softmax-aggregate + final linear + LayerNorm (H=2, dout=64).
// One node per 32-lane HALF; within a half, two 16-lane subgroups each own
// one edge per iteration (4 edges per wave-inst).  Lane owns 8 channels
// (ch0 = (l&15)*8); head = (l&15)>>3; dot-reduce = 3 xor steps within the
// 8-lane head group.  Gathers: uint4 (16B/lane, 64 lanes = 4 edge rows per
// VMEM inst), 6-deep (12 edges) in flight.  Cross-subgroup combine via one
// xor-16.  Wf pre-packed globally (aux), block prologue = plain 16KB copy.
// ---------------------------------------------------------------------------
__global__ __launch_bounds__(256, 6) void edge_fused(
    const u16* __restrict__ xl_p, const u16* __restrict__ xr_p,
    const float* __restrict__ att, const float* __restrict__ bias,
    const uint4* __restrict__ Wfp, const float* __restrict__ bf,
    const float* __restrict__ gamma, const float* __restrict__ beta,
    const int* __restrict__ offsets, const int* __restrict__ count,
    const int* __restrict__ src_sorted, float* __restrict__ out,
    int N, int ET)
{
    __shared__ uint4 sWp[32 * 32];      // 16 KB packed bf16 Wf
    __shared__ float sAgg[8][HD];       // 4 KB

    const int tid = threadIdx.x;
    for (int idx = tid; idx < 1024; idx += 256) sWp[idx] = Wfp[idx];
    __syncthreads();   // only block barrier

    const int l      = tid & 63;
    const int half   = tid >> 5;         // node slot 0..7 in block
    const int hl     = tid & 31;         // lane within half
    const int g16    = l & 15;           // lane within 16-group
    const int ch0    = g16 * 8;          // first of lane's 8 channels
    const int sgsel  = (l >> 4) & 1;     // subgroup within half
    const int sgbase = (l & 32) + sgsel; // shfl base for my edge index
    const int n      = blockIdx.x * 8 + half;
    const bool active = (n < N);

    // att (exp2 scale folded) and xr for my 8 channels
    float at[8], xr[8];
    {
        float4 a0 = *(const float4*)(att + ch0);
        float4 a1 = *(const float4*)(att + ch0 + 4);
        at[0] = a0.x * 1.44269504f; at[1] = a0.y * 1.44269504f;
        at[2] = a0.z * 1.44269504f; at[3] = a0.w * 1.44269504f;
        at[4] = a1.x * 1.44269504f; at[5] = a1.y * 1.44269504f;
        at[6] = a1.z * 1.44269504f; at[7] = a1.w * 1.44269504f;
        uint4 pr = make_uint4(0, 0, 0, 0);
        if (active) pr = *(const uint4*)(xr_p + (size_t)n * HD + ch0);
        xr[0] = lo_bf(pr.x); xr[1] = hi_bf(pr.x);
        xr[2] = lo_bf(pr.y); xr[3] = hi_bf(pr.y);
        xr[4] = lo_bf(pr.z); xr[5] = hi_bf(pr.z);
        xr[6] = lo_bf(pr.w); xr[7] = hi_bf(pr.w);
    }

    float acc[8] = {0.f, 0.f, 0.f, 0.f, 0.f, 0.f, 0.f, 0.f};
    float lden = 0.f;

    int beg = 0, cnt = 0;
    if (active) {
        beg = offsets[n];
        cnt = count[n] + 1;              // +1 self loop
        if ((u32)beg >= (u32)ET) beg = 0;
        if (cnt < 0) cnt = 0;
        if (cnt > ET - beg) cnt = ET - beg;
    }

    const char* xbase = (const char*)xl_p + ch0 * 2;   // lane's 16B within a row

#define EDGE_SCORE(Q, S)                                                   \
    {                                                                      \
        float t0 = lo_bf((Q).x) + xr[0]; t0 = fmaxf(t0, 0.2f * t0);        \
        float t1 = hi_bf((Q).x) + xr[1]; t1 = fmaxf(t1, 0.2f * t1);        \
        float t2 = lo_bf((Q).y) + xr[2]; t2 = fmaxf(t2, 0.2f * t2);        \
        float t3 = hi_bf((Q).y) + xr[3]; t3 = fmaxf(t3, 0.2f * t3);        \
        float t4 = lo_bf((Q).z) + xr[4]; t4 = fmaxf(t4, 0.2f * t4);        \
        float t5 = hi_bf((Q).z) + xr[5]; t5 = fmaxf(t5, 0.2f * t5);        \
        float t6 = lo_bf((Q).w) + xr[6]; t6 = fmaxf(t6, 0.2f * t6);        \
        float t7 = hi_bf((Q).w) + xr[7]; t7 = fmaxf(t7, 0.2f * t7);        \
        S = fmaf(t0, at[0], fmaf(t1, at[1], fmaf(t2, at[2], t3 * at[3]))); \
        S = fmaf(t4, at[4], fmaf(t5, at[5], fmaf(t6, at[6],                \
                 fmaf(t7, at[7], S))));                                    \
    }
#define EDGE_ACCUM(Q, P)                                                   \
    {                                                                      \
        lden += (P);                                                       \
        acc[0] = fmaf((P), lo_bf((Q).x), acc[0]);                          \
        acc[1] = fmaf((P), hi_bf((Q).x), acc[1]);                          \
        acc[2] = fmaf((P), lo_bf((Q).y), acc[2]);                          \
        acc[3] = fmaf((P), hi_bf((Q).y), acc[3]);                          \
        acc[4] = fmaf((P), lo_bf((Q).z), acc[4]);                          \
        acc[5] = fmaf((P), hi_bf((Q).z), acc[5]);                          \
        acc[6] = fmaf((P), lo_bf((Q).w), acc[6]);                          \
        acc[7] = fmaf((P), hi_bf((Q).w), acc[7]);                          \
    }

    int done = 0;
    while (done < cnt) {
        int chunk = cnt - done; if (chunk > 32) chunk = 32;
        int myidx = 0;
        if (hl < chunk) myidx = src_sorted[beg + done + hl];  // coalesced
        int j = 0;
        for (; j + 12 <= chunk; j += 12) {                    // 12 edges/half
            uint4 q[6];
            #pragma unroll
            for (int b = 0; b < 6; b++) {
                u32 off = (u32)__shfl(myidx, sgbase + j + 2 * b) << 8;
                q[b] = *(const uint4*)(xbase + off);
            }
            float sh[6];
            #pragma unroll
            for (int b = 0; b < 6; b++) EDGE_SCORE(q[b], sh[b]);
            #pragma unroll
            for (int m = 4; m; m >>= 1) {
                #pragma unroll
                for (int b = 0; b < 6; b++) sh[b] += __shfl_xor(sh[b], m);
            }
            #pragma unroll
            for (int b = 0; b < 6; b++) {
                float p = exp2f(sh[b]);
                EDGE_ACCUM(q[b], p);
            }
        }
        for (; j < chunk; j += 2) {                           // tail pairs
            u32 off = (u32)__shfl(myidx, sgbase + j) << 8;
            uint4 q = *(const uint4*)(xbase + off);
            float s;
            EDGE_SCORE(q, s);
            #pragma unroll
            for (int m = 4; m; m >>= 1) s += __shfl_xor(s, m);
            float p = (j + sgsel < chunk) ? exp2f(s) : 0.f;
            EDGE_ACCUM(q, p);
        }
        done += chunk;
    }
#undef EDGE_SCORE
#undef EDGE_ACCUM

    // combine the two subgroups of this half
    #pragma unroll
    for (int i = 0; i < 8; i++) acc[i] += __shfl_xor(acc[i], 16);
    lden += __shfl_xor(lden, 16);

    // normalize + bias, park in this half's sAgg slot (subgroup 0 writes)
    float rl = 1.f / fmaxf(lden, 1e-30f);
    if (!(l & 16)) {
        float4 b0 = *(const float4*)(bias + ch0);
        float4 b1 = *(const float4*)(bias + ch0 + 4);
        f32x4 v0, v1;
        v0[0] = acc[0] * rl + b0.x; v0[1] = acc[1] * rl + b0.y;
        v0[2] = acc[2] * rl + b0.z; v0[3] = acc[3] * rl + b0.w;
        v1[0] = acc[4] * rl + b1.x; v1[1] = acc[5] * rl + b1.y;
        v1[2] = acc[6] * rl + b1.z; v1[3] = acc[7] * rl + b1.w;
        *(f32x4*)&sAgg[half][ch0]     = v0;
        *(f32x4*)&sAgg[half][ch0 + 4] = v1;
    }
    asm volatile("s_waitcnt lgkmcnt(0)" ::: "memory");   // same-wave DS visibility

    // final linear: lane hl computes channels hl and hl+32
    float h0 = bf[hl], h1 = bf[hl + 32];
    #pragma unroll 8
    for (int k4 = 0; k4 < 32; k4++) {
        uint4 wp = sWp[k4 * 32 + hl];
        f32x4 ag = *(const f32x4*)&sAgg[half][k4 * 4];
        h0 = fmaf(ag[0], lo_bf(wp.x), h0);
        h0 = fmaf(ag[1], hi_bf(wp.x), h0);
        h0 = fmaf(ag[2], lo_bf(wp.y), h0);
        h0 = fmaf(ag[3], hi_bf(wp.y), h0);
        h1 = fmaf(ag[0], lo_bf(wp.z), h1);
        h1 = fmaf(ag[1], hi_bf(wp.z), h1);
        h1 = fmaf(ag[2], lo_bf(wp.w), h1);
        h1 = fmaf(ag[3], hi_bf(wp.w), h1);
    }

    float s1r = h0 + h1, s2r = h0 * h0 + h1 * h1;
    #pragma unroll
    for (int m = 16; m; m >>= 1) { s1r += __shfl_xor(s1r, m); s2r += __shfl_xor(s2r, m); }
    float mu  = s1r * (1.f / 64.f);
    float var = s2r * (1.f / 64.f) - mu * mu;
    float rs  = rsqrtf(fmaxf(var, 0.f) + 1e-5f);
    if (active) {
        out[(size_t)n * DOUT + hl]      = (h0 - mu) * rs * gamma[hl]      + beta[hl];
        out[(size_t)n * DOUT + hl + 32] = (h1 - mu) * rs * gamma[hl + 32] + beta[hl + 32];
    }
}

// ---------------------------------------------------------------------------
extern "C" void kernel_launch(void* const* d_in, const int* in_sizes, int n_in,
                              void* d_out, int out_size, void* d_ws, size_t ws_size,
                              hipStream_t stream) {
    const float* X    = (const float*)d_in[0];
    const int*   E    = (const int*)d_in[1];
    const float* attr = (const float*)d_in[2];
    const float* Wl   = (const float*)d_in[3];
    const float* bl   = (const float*)d_in[4];
    const float* Wr   = (const float*)d_in[5];
    const float* br   = (const float*)d_in[6];
    const float* att  = (const float*)d_in[7];
    const float* bias = (const float*)d_in[8];
    const float* Wf   = (const float*)d_in[9];
    const float* bf   = (const float*)d_in[10];
    const float* gamma= (const float*)d_in[11];
    const float* beta = (const float*)d_in[12];
    float* out = (float*)d_out;

    const int N  = in_sizes[0] / DIN;
    const int NE = in_sizes[1] / 2;
    const int ET = NE + N;
    const int G  = (N + 255) / 256;   // scan blocks

    char* ws = (char*)d_ws;
    int* count      = (int*)ws;               ws += (size_t)N * 4;
    int* cursor     = (int*)ws;               ws += (size_t)N * 4;
    int* offsets    = (int*)ws;               ws += (size_t)N * 4;
    int* bsum       = (int*)ws;               ws += (size_t)G * 4;
    int* bsum_ex    = (int*)ws;               ws += (size_t)G * 4;
    int* src_sorted = (int*)ws;               ws += (size_t)ET * 4;
    u16* xl_p       = (u16*)ws;               ws += (size_t)N * HD * 2;
    u16* xr_p       = (u16*)ws;               ws += (size_t)N * HD * 2;
    u16* WTl        = (u16*)ws;               ws += 128 * 128 * 2;
    u16* WTr        = (u16*)ws;               ws += 128 * 128 * 2;
    uint4* Wfp      = (uint4*)ws;             ws += 1024 * 16;

    // count + cursor zeroed in one launch (adjacent); self-loop +1 folded
    // into the scans / edge_fused.
    zero_counts<<<(2 * N + 255) / 256, 256, 0, stream>>>(count, 2 * N);

    const int aux_items = 33792 + 4 * NE;     // WT(32K) + Wfp(1K) + hist + pass
    aux_prep<<<(aux_items + 255) / 256, 256, 0, stream>>>(
        Wl, Wr, Wf, E, attr, WTl, WTr, Wfp, count, out, N, NE);

    gemm1<<<dim3((N + 63) / 64, 2), 256, 0, stream>>>(X, WTl, bl, WTr, br, xl_p, xr_p, N);
    scan1<<<G, 256, 0, stream>>>(count, bsum, N);
    scan2<<<1, 1024, 0, stream>>>(bsum, bsum_ex, G);
    scan3<<<G, 256, 0, stream>>>(count, bsum_ex, offsets, N);
    scatter<<<(ET + 255) / 256, 256, 0, stream>>>(E, offsets, cursor, src_sorted, N, NE, ET);

    edge_fused<<<(N + 7) / 8, 256, 0, stream>>>(
        xl_p, xr_p, att, bias, Wfp, bf, gamma, beta,
        offsets, count, src_sorted, out, N, ET);
}